// Round 9
// baseline (230.356 us; speedup 1.0000x reference)
//
#include <hip/hip_runtime.h>

#define NB   64
#define NT   256
#define NI   512
#define NO   512
#define NOBS 128
#define ETA  0.01f

typedef __attribute__((ext_vector_type(8))) short bf16x8;
typedef __attribute__((ext_vector_type(4))) float f32x4;

#define X4_COUNT  (NB*NT*NI/4)
#define WG4_COUNT (NB*NOBS*NI/4)
#define K0_TOTAL  (X4_COUNT + WG4_COUNT)

__device__ __forceinline__ unsigned short f2bf(float f) {
    unsigned int u = __float_as_uint(f);
    return (unsigned short)((u + 0x7fffu + ((u >> 16) & 1u)) >> 16); // RNE
}

// ---------------- K0: X -> bf16 ; gather obs rows of W -> bf16 ----------------
__global__ __launch_bounds__(256)
void k0_convert(const float* __restrict__ X, const float* __restrict__ Wi,
                const int* __restrict__ obs,
                unsigned short* __restrict__ Xb, unsigned short* __restrict__ Wg)
{
    int idx = blockIdx.x * 256 + threadIdx.x;
    const int stride = gridDim.x * 256;
    for (; idx < K0_TOTAL; idx += stride) {
        float4 v; ushort4* dst;
        if (idx < X4_COUNT) {
            v = ((const float4*)X)[idx];
            dst = (ushort4*)Xb + idx;
        } else {
            int g = idx - X4_COUNT;
            int row = g >> 7, pos = g & 127;
            int b = row >> 7, j = row & 127;
            v = ((const float4*)(Wi + ((size_t)b * NO + obs[j]) * NI))[pos];
            dst = (ushort4*)Wg + ((size_t)row * 128 + pos);
        }
        *dst = make_ushort4(f2bf(v.x), f2bf(v.y), f2bf(v.z), f2bf(v.w));
    }
}

// ---------------- K1: LDS-tiled bf16 MFMA GEMM ----------------
// 5 blocks/batch: sub 0->(0,0) 1->(1,0) 2->(1,1) of G (diag + lower only;
// k2 never reads the upper block), sub 3..4 -> P0 row-blocks {0,1}.
__global__ __launch_bounds__(256)
void k1_gemm(const unsigned short* __restrict__ Xb,
             const unsigned short* __restrict__ Wg,
             float* __restrict__ G, float* __restrict__ P0)
{
    __shared__ unsigned short As[128 * 64];
    __shared__ unsigned short Bs[128 * 64];

    const int tid  = threadIdx.x;
    const int lane = tid & 63;
    const int wv   = tid >> 6;
    const int l16  = lane & 15;
    const int quad = lane >> 4;

    const int b   = blockIdx.x & 63;   // same-batch blocks -> same XCD
    const int sub = blockIdx.x >> 6;   // 0..4

    const unsigned short* xbB = Xb + (size_t)b * NT * NI;
    const unsigned short *aRows, *bRows;
    float* outp;
    int ldo;
    if (sub < 3) {
        const int bm = (sub >= 1) ? 1 : 0;
        const int bn = (sub == 2) ? 1 : 0;
        aRows = xbB + (size_t)bm * 128 * NI;
        bRows = xbB + (size_t)bn * 128 * NI;
        outp  = G + (size_t)b * NT * NT + (size_t)bm * 128 * NT + bn * 128;
        ldo   = NT;
    } else {
        const int pb = sub - 3;
        aRows = xbB + (size_t)pb * 128 * NI;
        bRows = Wg + (size_t)b * NOBS * NI;
        outp  = P0 + (size_t)b * NT * NOBS + (size_t)pb * 128 * NOBS;
        ldo   = NOBS;
    }

    const int wm = (wv >> 1) * 64;
    const int wn = (wv & 1) * 64;

    f32x4 acc[4][4] = {};

    for (int kb = 0; kb < NI / 64; ++kb) {
        __syncthreads();
#pragma unroll
        for (int it = 0; it < 4; ++it) {
            const int s = it * 256 + tid;
            const int m = s >> 3, c = s & 7;
            const int slot = m * 64 + ((c ^ (m & 7)) * 8);
            const size_t goff = (size_t)m * NI + kb * 64 + c * 8;
            *(bf16x8*)&As[slot] = *(const bf16x8*)(aRows + goff);
            *(bf16x8*)&Bs[slot] = *(const bf16x8*)(bRows + goff);
        }
        __syncthreads();
#pragma unroll
        for (int ks = 0; ks < 2; ++ks) {
            const int q = ks * 4 + quad;
            bf16x8 af[4], bfr[4];
#pragma unroll
            for (int mt = 0; mt < 4; ++mt) {
                const int m = wm + mt * 16 + l16;
                af[mt] = *(const bf16x8*)&As[m * 64 + ((q ^ (m & 7)) * 8)];
            }
#pragma unroll
            for (int nt = 0; nt < 4; ++nt) {
                const int n = wn + nt * 16 + l16;
                bfr[nt] = *(const bf16x8*)&Bs[n * 64 + ((q ^ (n & 7)) * 8)];
            }
#pragma unroll
            for (int mt = 0; mt < 4; ++mt)
#pragma unroll
                for (int nt = 0; nt < 4; ++nt)
                    acc[mt][nt] = __builtin_amdgcn_mfma_f32_16x16x32_bf16(
                        af[mt], bfr[nt], acc[mt][nt], 0, 0, 0);
        }
    }

#pragma unroll
    for (int mt = 0; mt < 4; ++mt)
#pragma unroll
        for (int nt = 0; nt < 4; ++nt)
#pragma unroll
            for (int r = 0; r < 4; ++r)
                outp[(size_t)(wm + mt * 16 + quad * 4 + r) * ldo
                     + wn + nt * 16 + l16] = acc[mt][nt][r];
}

// ---------------- K2: register-resident blocked scan ----------------
// block = (b, 64 j's) -> 128 blocks, 512 threads, lane = j.
// Wave w owns rows [32w, 32w+32) of pre in REGISTERS (aLo/aHi float[16]).
// Chunk c: owner wave (c>>1) runs 16 serial sigmoid steps on its own half,
// broadcasts Y via LDS; barrier; every wave applies Y_c to its future halves
// (G rows wave-uniform -> s_load; fma streams independent across 16 rows).
__device__ __forceinline__ void serial16(float (&pre)[16], const float* gd,
                                         float* ybp, float* obp, int j)
{
#pragma unroll
    for (int u = 0; u < 16; ++u) {
        const float y = 1.f / (1.f + __expf(-pre[u]));
        ybp[u * 64 + j] = y;
        obp[(size_t)u * NOBS] = y;
        const float e = ETA * y;
#pragma unroll
        for (int v = u + 1; v < 16; ++v)
            pre[v] = fmaf(e, gd[u * 16 + v], pre[v]);
    }
}

__device__ __forceinline__ void update16(float (&pre)[16], const float* grow0,
                                         const float (&ey)[16])
{
#pragma unroll
    for (int r = 0; r < 16; ++r) {
        const float* gr = grow0 + (size_t)r * NT;   // wave-uniform -> s_load
        float a0 = pre[r], a1 = 0.f, a2 = 0.f, a3 = 0.f;
#pragma unroll
        for (int u = 0; u < 16; u += 4) {
            a0 = fmaf(ey[u],     gr[u],     a0);
            a1 = fmaf(ey[u + 1], gr[u + 1], a1);
            a2 = fmaf(ey[u + 2], gr[u + 2], a2);
            a3 = fmaf(ey[u + 3], gr[u + 3], a3);
        }
        pre[r] = (a0 + a1) + (a2 + a3);
    }
}

__global__ __launch_bounds__(512)
void k2_scan(const float* __restrict__ G, const float* __restrict__ P0,
             float* __restrict__ out)
{
    __shared__ float gdiag[16 * 16 * 16];  // 16 KB [c][u][v]
    __shared__ float yb[16 * 64];          //  4 KB [u][j]

    const int tid = threadIdx.x;
    const int j   = tid & 63;
    const int w   = __builtin_amdgcn_readfirstlane(tid >> 6);  // uniform wave id

    const int b  = blockIdx.x & 63;        // same-batch blocks -> same XCD
    const int jb = blockIdx.x >> 6;        // 0..1

    const float* Gb = G  + (size_t)b * NT * NT;
    const float* Pb = P0 + (size_t)b * NT * NOBS + jb * 64 + j;
    float*       ob = out + (size_t)b * NT * NOBS + jb * 64 + j;

    const int r0 = w * 32;
    float aLo[16], aHi[16];
#pragma unroll
    for (int r = 0; r < 16; ++r) aLo[r] = Pb[(size_t)(r0 + r) * NOBS];
#pragma unroll
    for (int r = 0; r < 16; ++r) aHi[r] = Pb[(size_t)(r0 + 16 + r) * NOBS];

#pragma unroll
    for (int p = 0; p < 2; ++p) {
        const int fi = p * 512 + tid;      // 1024 f32x4
        const int cc = fi >> 6, u = (fi >> 2) & 15, v4 = fi & 3;
        ((f32x4*)gdiag)[fi] =
            *(const f32x4*)(Gb + (size_t)(cc * 16 + u) * NT + cc * 16 + v4 * 4);
    }
    __syncthreads();

    for (int c = 0; c < 16; ++c) {
        if (w == (c >> 1)) {
            if (c & 1) serial16(aHi, gdiag + c * 256, yb,
                                ob + (size_t)c * 16 * NOBS, j);
            else       serial16(aLo, gdiag + c * 256, yb,
                                ob + (size_t)c * 16 * NOBS, j);
        }
        __syncthreads();
        float ey[16];
#pragma unroll
        for (int u = 0; u < 16; ++u) ey[u] = ETA * yb[u * 64 + j];
        const float* gc = Gb + c * 16;
        if (2 * w >= c + 1)     update16(aLo, gc + (size_t)r0 * NT, ey);
        if (2 * w + 1 >= c + 1) update16(aHi, gc + (size_t)(r0 + 16) * NT, ey);
        __syncthreads();
    }
}

extern "C" void kernel_launch(void* const* d_in, const int* in_sizes, int n_in,
                              void* d_out, int out_size, void* d_ws, size_t ws_size,
                              hipStream_t stream)
{
    const float* X   = (const float*)d_in[0];
    const float* Wi  = (const float*)d_in[1];
    const int*   obs = (const int*)d_in[2];
    float*       out = (float*)d_out;

    float*          G  = (float*)d_ws;                           // 16 MB
    float*          P0 = (float*)((char*)d_ws + (16u << 20));    //  8 MB
    unsigned short* Xb = (unsigned short*)((char*)d_ws + (24u << 20)); // 16 MB
    unsigned short* Wg = (unsigned short*)((char*)d_ws + (40u << 20)); //  8 MB

    hipLaunchKernelGGL(k0_convert, dim3(3072), dim3(256), 0, stream,
                       X, Wi, obs, Xb, Wg);
    hipLaunchKernelGGL(k1_gemm, dim3(NB * 5), dim3(256), 0, stream,
                       Xb, Wg, G, P0);
    hipLaunchKernelGGL(k2_scan, dim3(NB * 2), dim3(512), 0, stream,
                       G, P0, out);
}

// Round 10
// 168.099 us; speedup vs baseline: 1.3704x; 1.3704x over previous
//
#include <hip/hip_runtime.h>

#define NB   64
#define NT   256
#define NI   512
#define NO   512
#define NOBS 128
#define ETA  0.01f

typedef __attribute__((ext_vector_type(8))) short bf16x8;
typedef __attribute__((ext_vector_type(4))) float f32x4;

#define X4_COUNT  (NB*NT*NI/4)
#define WG4_COUNT (NB*NOBS*NI/4)
#define K0_TOTAL  (X4_COUNT + WG4_COUNT)

__device__ __forceinline__ unsigned short f2bf(float f) {
    unsigned int u = __float_as_uint(f);
    return (unsigned short)((u + 0x7fffu + ((u >> 16) & 1u)) >> 16); // RNE
}

// ---------------- K0: X -> bf16 ; gather obs rows of W -> bf16 ----------------
__global__ __launch_bounds__(256)
void k0_convert(const float* __restrict__ X, const float* __restrict__ Wi,
                const int* __restrict__ obs,
                unsigned short* __restrict__ Xb, unsigned short* __restrict__ Wg)
{
    int idx = blockIdx.x * 256 + threadIdx.x;
    const int stride = gridDim.x * 256;
    for (; idx < K0_TOTAL; idx += stride) {
        float4 v; ushort4* dst;
        if (idx < X4_COUNT) {
            v = ((const float4*)X)[idx];
            dst = (ushort4*)Xb + idx;
        } else {
            int g = idx - X4_COUNT;
            int row = g >> 7, pos = g & 127;
            int b = row >> 7, j = row & 127;
            v = ((const float4*)(Wi + ((size_t)b * NO + obs[j]) * NI))[pos];
            dst = (ushort4*)Wg + ((size_t)row * 128 + pos);
        }
        *dst = make_ushort4(f2bf(v.x), f2bf(v.y), f2bf(v.z), f2bf(v.w));
    }
}

// ---------------- K1: LDS-tiled bf16 MFMA GEMM ----------------
// 5 blocks/batch: sub 0->(0,0) 1->(1,0) 2->(1,1) of G -> writes bf16 Gh (all)
// + fp32 Gd for diagonal 16-tiles. sub 3..4 -> P0 row-blocks {0,1} (fp32).
__global__ __launch_bounds__(256)
void k1_gemm(const unsigned short* __restrict__ Xb,
             const unsigned short* __restrict__ Wg,
             float* __restrict__ Gd, unsigned short* __restrict__ Gh,
             float* __restrict__ P0)
{
    __shared__ unsigned short As[128 * 64];
    __shared__ unsigned short Bs[128 * 64];

    const int tid  = threadIdx.x;
    const int lane = tid & 63;
    const int wv   = tid >> 6;
    const int l16  = lane & 15;
    const int quad = lane >> 4;

    const int b   = blockIdx.x & 63;   // same-batch blocks -> same XCD
    const int sub = blockIdx.x >> 6;   // 0..4

    const unsigned short* xbB = Xb + (size_t)b * NT * NI;
    const unsigned short *aRows, *bRows;
    int bm = 0, bn = 0;
    if (sub < 3) {
        bm = (sub >= 1) ? 1 : 0;
        bn = (sub == 2) ? 1 : 0;
        aRows = xbB + (size_t)bm * 128 * NI;
        bRows = xbB + (size_t)bn * 128 * NI;
    } else {
        const int pb = sub - 3;
        bm = pb;
        aRows = xbB + (size_t)pb * 128 * NI;
        bRows = Wg + (size_t)b * NOBS * NI;
    }

    const int wm = (wv >> 1) * 64;
    const int wn = (wv & 1) * 64;

    f32x4 acc[4][4] = {};

    for (int kb = 0; kb < NI / 64; ++kb) {
        __syncthreads();
#pragma unroll
        for (int it = 0; it < 4; ++it) {
            const int s = it * 256 + tid;
            const int m = s >> 3, c = s & 7;
            const int slot = m * 64 + ((c ^ (m & 7)) * 8);
            const size_t goff = (size_t)m * NI + kb * 64 + c * 8;
            *(bf16x8*)&As[slot] = *(const bf16x8*)(aRows + goff);
            *(bf16x8*)&Bs[slot] = *(const bf16x8*)(bRows + goff);
        }
        __syncthreads();
#pragma unroll
        for (int ks = 0; ks < 2; ++ks) {
            const int q = ks * 4 + quad;
            bf16x8 af[4], bfr[4];
#pragma unroll
            for (int mt = 0; mt < 4; ++mt) {
                const int m = wm + mt * 16 + l16;
                af[mt] = *(const bf16x8*)&As[m * 64 + ((q ^ (m & 7)) * 8)];
            }
#pragma unroll
            for (int nt = 0; nt < 4; ++nt) {
                const int n = wn + nt * 16 + l16;
                bfr[nt] = *(const bf16x8*)&Bs[n * 64 + ((q ^ (n & 7)) * 8)];
            }
#pragma unroll
            for (int mt = 0; mt < 4; ++mt)
#pragma unroll
                for (int nt = 0; nt < 4; ++nt)
                    acc[mt][nt] = __builtin_amdgcn_mfma_f32_16x16x32_bf16(
                        af[mt], bfr[nt], acc[mt][nt], 0, 0, 0);
        }
    }

    if (sub < 3) {
        unsigned short* GhB = Gh + ((size_t)b << 16);
        float* GdB = Gd + ((size_t)b << 12);
#pragma unroll
        for (int mt = 0; mt < 4; ++mt)
#pragma unroll
            for (int nt = 0; nt < 4; ++nt) {
                const int gcol = bn * 128 + wn + nt * 16 + l16;
#pragma unroll
                for (int r = 0; r < 4; ++r) {
                    const int grow = bm * 128 + wm + mt * 16 + quad * 4 + r;
                    const float v = acc[mt][nt][r];
                    GhB[(size_t)grow * 256 + gcol] = f2bf(v);
                    if ((grow >> 4) == (gcol >> 4))
                        GdB[((grow >> 4) << 8) + ((grow & 15) << 4) + (gcol & 15)] = v;
                }
            }
    } else {
        float* Pb = P0 + (size_t)b * NT * NOBS + (size_t)bm * 128 * NOBS;
#pragma unroll
        for (int mt = 0; mt < 4; ++mt)
#pragma unroll
            for (int nt = 0; nt < 4; ++nt)
#pragma unroll
                for (int r = 0; r < 4; ++r)
                    Pb[(size_t)(wm + mt * 16 + quad * 4 + r) * NOBS
                       + wn + nt * 16 + l16] = acc[mt][nt][r];
    }
}

// ---------------- K2: MFMA-accelerated blocked scan ----------------
// block = (b, 32 j's) -> 256 blocks, 512 threads (8 waves).
// Wave w holds pre tiles T=2w,2w+1 as MFMA C-fragments (f32x4 x2 ntiles each).
// Chunk c (16 t's): owner wave (c>>1) dumps tile c to LDS, 32 lanes run the
// serial sigmoid scan (fp32 gdiag), write out + packed bf16 eta*y; then all
// waves update future tiles T>c with mfma_16x16x32_bf16 (upper K-half zeroed).
__global__ __launch_bounds__(512)
void k2_scan(const float* __restrict__ Gd, const unsigned short* __restrict__ Gh,
             const float* __restrict__ P0, float* __restrict__ out)
{
    __shared__ float gdiag[16 * 16 * 16];   // 16 KB [c][u][v] fp32
    __shared__ float preS[16 * 32];         //  2 KB [u][j]
    __shared__ unsigned int ybf2[2 * 8 * 32]; // 2 KB ping-pong packed eta*y pairs

    const int tid  = threadIdx.x;
    const int lane = tid & 63;
    const int l16  = lane & 15;
    const int quad = lane >> 4;
    const int w    = __builtin_amdgcn_readfirstlane(tid >> 6);

    const int b  = blockIdx.x & 63;         // same-batch blocks -> same XCD
    const int jg = blockIdx.x >> 6;         // 0..3

    const float* Pb = P0 + (size_t)b * NT * NOBS + jg * 32;
    const unsigned short* GhB = Gh + ((size_t)b << 16);
    float* ob = out + (size_t)b * NT * NOBS + jg * 32;

    // stage fp32 diag tiles (Gd[b] is 16 KB contiguous)
    {
        const f32x4* gs = (const f32x4*)(Gd + ((size_t)b << 12));
        ((f32x4*)gdiag)[tid]       = gs[tid];
        ((f32x4*)gdiag)[512 + tid] = gs[512 + tid];
    }

    // init pre C-fragments from P0: D[m=quad*4+r][n=l16]
    f32x4 acc[2][2];
#pragma unroll
    for (int s2 = 0; s2 < 2; ++s2)
#pragma unroll
        for (int nt = 0; nt < 2; ++nt)
#pragma unroll
            for (int r = 0; r < 4; ++r)
                acc[s2][nt][r] =
                    Pb[(size_t)(w * 32 + s2 * 16 + quad * 4 + r) * NOBS
                       + nt * 16 + l16];

#pragma unroll
    for (int c = 0; c < 16; ++c) {
        const int cp = c & 1;
        // ---- phase A: owner dumps tile c to LDS ----
        if (w == (c >> 1)) {
#pragma unroll
            for (int nt = 0; nt < 2; ++nt)
#pragma unroll
                for (int r = 0; r < 4; ++r)
                    preS[(quad * 4 + r) * 32 + nt * 16 + l16] = acc[cp][nt][r];
        }
        __syncthreads();
        // ---- phase B: serial sigmoid scan on 32 lanes ----
        if (w == (c >> 1) && lane < 32) {
            const int j = lane;
            float p[16];
#pragma unroll
            for (int u = 0; u < 16; ++u) p[u] = preS[u * 32 + j];
            const float* gdc = gdiag + c * 256;
            float eprev = 0.f;
#pragma unroll
            for (int u = 0; u < 16; ++u) {
                const float y = 1.f / (1.f + __expf(-p[u]));
                ob[(size_t)(c * 16 + u) * NOBS + j] = y;
                const float e = ETA * y;
#pragma unroll
                for (int v = u + 1; v < 16; ++v)
                    p[v] = fmaf(e, gdc[u * 16 + v], p[v]);
                if (u & 1)
                    ybf2[cp * 256 + (u >> 1) * 32 + j] =
                        (unsigned)f2bf(eprev) | ((unsigned)f2bf(e) << 16);
                else
                    eprev = e;
            }
        }
        __syncthreads();
        // ---- phase C: MFMA rank-16 update of future tiles ----
        if (c < 15) {
            union { bf16x8 v; unsigned int d[4]; } B0, B1;
#pragma unroll
            for (int p2 = 0; p2 < 4; ++p2) { B0.d[p2] = 0; B1.d[p2] = 0; }
            if (quad < 2) {
#pragma unroll
                for (int p2 = 0; p2 < 4; ++p2) {
                    B0.d[p2] = ybf2[cp * 256 + (quad * 4 + p2) * 32 + l16];
                    B1.d[p2] = ybf2[cp * 256 + (quad * 4 + p2) * 32 + 16 + l16];
                }
            }
#pragma unroll
            for (int s2 = 0; s2 < 2; ++s2) {
                const int T = 2 * w + s2;
                if (T > c) {
                    union { bf16x8 v; unsigned int d[4]; } A;
#pragma unroll
                    for (int p2 = 0; p2 < 4; ++p2) A.d[p2] = 0;
                    if (quad < 2)
                        A.v = *(const bf16x8*)(GhB + (size_t)(T * 16 + l16) * 256
                                               + c * 16 + quad * 8);
                    acc[s2][0] = __builtin_amdgcn_mfma_f32_16x16x32_bf16(
                        A.v, B0.v, acc[s2][0], 0, 0, 0);
                    acc[s2][1] = __builtin_amdgcn_mfma_f32_16x16x32_bf16(
                        A.v, B1.v, acc[s2][1], 0, 0, 0);
                }
            }
        }
    }
}

extern "C" void kernel_launch(void* const* d_in, const int* in_sizes, int n_in,
                              void* d_out, int out_size, void* d_ws, size_t ws_size,
                              hipStream_t stream)
{
    const float* X   = (const float*)d_in[0];
    const float* Wi  = (const float*)d_in[1];
    const int*   obs = (const int*)d_in[2];
    float*       out = (float*)d_out;

    float*          Gd = (float*)d_ws;                                  //  1 MB
    float*          P0 = (float*)((char*)d_ws + (1u << 20));            //  8 MB
    unsigned short* Gh = (unsigned short*)((char*)d_ws + (9u << 20));   //  8 MB
    unsigned short* Xb = (unsigned short*)((char*)d_ws + (17u << 20));  // 16 MB
    unsigned short* Wg = (unsigned short*)((char*)d_ws + (33u << 20));  //  8 MB

    hipLaunchKernelGGL(k0_convert, dim3(3072), dim3(256), 0, stream,
                       X, Wi, obs, Xb, Wg);
    hipLaunchKernelGGL(k1_gemm, dim3(NB * 5), dim3(256), 0, stream,
                       Xb, Wg, Gd, Gh, P0);
    hipLaunchKernelGGL(k2_scan, dim3(NB * 4), dim3(512), 0, stream,
                       Gd, Gh, P0, out);
}